// Round 6
// baseline (313.294 us; speedup 1.0000x reference)
//
#include <hip/hip_runtime.h>
#include <hip/hip_bf16.h>

// Problem constants (match reference)
#define Bb   32
#define Nn   65536
#define Dd   16
#define Hh   64
#define Mm   32
#define OUTn 3

#define NPW   256              // nodes per wave in mphase
#define WPB_N (Nn / NPW)       // waves per batch = 256
#define TPB   256
#define NSEG  65               // 64 knots -> 65 segments

typedef __attribute__((ext_vector_type(8)))  __bf16 bf16x8;
typedef __attribute__((ext_vector_type(4)))  __bf16 bf16x4;
typedef __attribute__((ext_vector_type(16))) float  f32x16;
typedef __attribute__((ext_vector_type(4)))  float  f32x4;

static __device__ inline void split_bf(float w, __bf16& hi, __bf16& lo) {
    hi = (__bf16)w;                 // RNE hardware cvt
    lo = (__bf16)(w - (float)hi);   // residual
}

// ---------------------------------------------------------------------------
// Phase 1 via MFMA. Changes vs R5:
//  * 1-deep register prefetch of next tile (keeps ~2KiB/wave in flight)
//  * persistent broadcast bias vector as MFMA C-in (no per-tile acc init movs)
//  * relu + tree-sum in place on the accumulator (no temps)
//  * __launch_bounds__(256,4): pin >=4 waves/SIMD (<=128 VGPR)
__global__ __launch_bounds__(TPB, 4) void k_mphase(
    const float* __restrict__ in, const float* __restrict__ mw1,
    const float* __restrict__ mb1, float* __restrict__ partials,
    __bf16* __restrict__ xlast)
{
    const int lane = threadIdx.x & 63;
    const int l31  = lane & 31;
    const int half = lane >> 5;                        // k-part: feats 8*half..
    const int wid  = blockIdx.x * (TPB / 64) + (threadIdx.x >> 6);
    const size_t node0 = (size_t)wid * NPW;

    // B fragments: B[k][col], k = 8*half + e. hi/lo split kills weight bias.
    bf16x8 bhiA, bloA, bhiB, bloB;
#pragma unroll
    for (int e = 0; e < 8; ++e) {
        const int k = 8 * half + e;
        __bf16 h, l;
        split_bf(mw1[k * Hh + l31], h, l);        bhiA[e] = h; bloA[e] = l;
        split_bf(mw1[k * Hh + 32 + l31], h, l);   bhiB[e] = h; bloB[e] = l;
    }
    // persistent bias vectors (C-in for the first MFMA of each chain)
    const float biasA = mb1[l31];
    const float biasB = mb1[32 + l31];
    f32x16 bvA, bvB;
#pragma unroll
    for (int r = 0; r < 16; ++r) { bvA[r] = biasA; bvB[r] = biasB; }

    float hsumA = 0.f, hsumB = 0.f;
    const float* __restrict__ inw = in + node0 * Dd + (size_t)l31 * Dd + 8 * half;

    // prefetch tile 0
    f32x4 c0 = *(const f32x4*)(inw);
    f32x4 c1 = *(const f32x4*)(inw + 4);

#pragma unroll
    for (int s = 0; s < NPW / 32; ++s) {               // 8 tiles of 32 nodes
        f32x4 n0, n1;
        if (s < NPW / 32 - 1) {                        // prefetch tile s+1
            const float* apn = inw + (size_t)(s + 1) * 32 * Dd;
            n0 = *(const f32x4*)(apn);
            n1 = *(const f32x4*)(apn + 4);
        }

        bf16x8 a;
        a[0] = (__bf16)c0[0]; a[1] = (__bf16)c0[1];
        a[2] = (__bf16)c0[2]; a[3] = (__bf16)c0[3];
        a[4] = (__bf16)c1[0]; a[5] = (__bf16)c1[1];
        a[6] = (__bf16)c1[2]; a[7] = (__bf16)c1[3];

        f32x16 accA = __builtin_amdgcn_mfma_f32_32x32x16_bf16(a, bloA, bvA, 0, 0, 0);
        accA        = __builtin_amdgcn_mfma_f32_32x32x16_bf16(a, bhiA, accA, 0, 0, 0);
        f32x16 accB = __builtin_amdgcn_mfma_f32_32x32x16_bf16(a, bloB, bvB, 0, 0, 0);
        accB        = __builtin_amdgcn_mfma_f32_32x32x16_bf16(a, bhiB, accB, 0, 0, 0);

        // relu + tree-sum in place
#pragma unroll
        for (int r = 0; r < 16; ++r) {
            accA[r] = fmaxf(accA[r], 0.f);
            accB[r] = fmaxf(accB[r], 0.f);
        }
#pragma unroll
        for (int st = 8; st >= 1; st >>= 1)
#pragma unroll
            for (int r = 0; r < st; ++r) {
                accA[r] += accA[r + st];
                accB[r] += accB[r + st];
            }
        hsumA += accA[0]; hsumB += accB[0];

        // x_last: lanes>=32 hold feat 15 of node (s*32 + l31) in c1.w
        float x15 = __shfl_xor(c1[3], 32, 64);
        if (lane < 32) xlast[node0 + (size_t)s * 32 + lane] = (__bf16)x15;

        c0 = n0; c1 = n1;
    }

    hsumA += __shfl_xor(hsumA, 32, 64);
    hsumB += __shfl_xor(hsumB, 32, 64);
    partials[(size_t)wid * Hh + lane] = (lane < 32) ? hsumA : hsumB;
}

// ---------------------------------------------------------------------------
// Reduce partials (parallel, coalesced) + build PWL tables.
// One block (256 thr) per batch. out_j(x) = A_j[seg] + B_j[seg]*x.
__global__ __launch_bounds__(256) void k_combine(
    const float* __restrict__ partials,
    const float* __restrict__ mw2, const float* __restrict__ mb2,
    const float* __restrict__ iw1, const float* __restrict__ ib1,
    const float* __restrict__ iw2, const float* __restrict__ ib2,
    float* __restrict__ knotsG, float* __restrict__ segG)
{
    __shared__ float red[4][Hh];
    __shared__ float sHs[Hh], sMs[Mm], sBase[Hh], sW[Hh], sKn[Hh], sSort[Hh];
    __shared__ float sIw2[Hh * OUTn];
    const int b = blockIdx.x;
    const int t = threadIdx.x;              // 0..255
    const int h = t & 63, slice = t >> 6;   // 4 slices x 64 h

    float s = 0.f;
    const float* p = partials + ((size_t)b * WPB_N + slice * 64) * Hh + h;
#pragma unroll 8
    for (int w = 0; w < 64; ++w) s += p[(size_t)w * Hh];
    red[slice][h] = s;
    for (int i = t; i < Hh * OUTn; i += 256) sIw2[i] = iw2[i];
    __syncthreads();

    if (t < Hh) sHs[t] = red[0][t] + red[1][t] + red[2][t] + red[3][t];
    __syncthreads();

    if (t < Mm) {
        float v = (float)Nn * mb2[t];
        for (int hh = 0; hh < Hh; ++hh) v = fmaf(sHs[hh], mw2[hh * Mm + t], v);
        sMs[t] = v;
    }
    __syncthreads();

    if (t < Hh) {
        float bs = ib1[t];
        for (int m = 0; m < Mm; ++m) bs = fmaf(sMs[m], iw1[m * Hh + t], bs);
        float w = iw1[Mm * Hh + t];
        sBase[t] = bs; sW[t] = w;
        float k = (w != 0.f) ? (-bs / w) : 1e15f;
        if (!(fabsf(k) < 1e15f)) k = 1e15f;   // NaN/inf guard
        sKn[t] = k;
    }
    __syncthreads();

    if (t < Hh) {                            // rank sort (64 values)
        float k = sKn[t];
        int r = 0;
        for (int j = 0; j < Hh; ++j) {
            float kj = sKn[j];
            r += (kj < k || (kj == k && j < t)) ? 1 : 0;
        }
        sSort[r] = k;
    }
    __syncthreads();

    if (t < Hh) knotsG[(size_t)b * Hh + t] = sSort[t];
    if (t < NSEG) {
        float lo = (t == 0)  ? sSort[0] - 1.0f      : sSort[t - 1];
        float hi = (t == Hh) ? sSort[Hh - 1] + 1.0f : sSort[t];
        float m  = 0.5f * lo + 0.5f * hi;
        float A0 = ib2[0], A1 = ib2[1], A2 = ib2[2], B0 = 0.f, B1 = 0.f, B2 = 0.f;
        for (int hh = 0; hh < Hh; ++hh) {
            float bs = sBase[hh], w = sW[hh];
            if (fmaf(w, m, bs) > 0.f) {
                A0 = fmaf(bs, sIw2[hh * 3 + 0], A0);
                A1 = fmaf(bs, sIw2[hh * 3 + 1], A1);
                A2 = fmaf(bs, sIw2[hh * 3 + 2], A2);
                B0 = fmaf(w,  sIw2[hh * 3 + 0], B0);
                B1 = fmaf(w,  sIw2[hh * 3 + 1], B1);
                B2 = fmaf(w,  sIw2[hh * 3 + 2], B2);
            }
        }
        float* sg = segG + (size_t)b * 6 * NSEG;   // SoA: [6][NSEG]
        sg[0 * NSEG + t] = A0; sg[1 * NSEG + t] = A1; sg[2 * NSEG + t] = A2;
        sg[3 * NSEG + t] = B0; sg[4 * NSEG + t] = B1; sg[5 * NSEG + t] = B2;
    }
}

// ---------------------------------------------------------------------------
// Phase 2: PWL eval. 4 nodes/thread; branchless binary search over 64 knots.
__global__ __launch_bounds__(TPB) void k_iphase(
    const __bf16* __restrict__ xl, const float* __restrict__ knotsG,
    const float* __restrict__ segG, float* __restrict__ out)
{
    __shared__ __align__(16) float sK[Hh];
    __shared__ float sT[6 * NSEG];
    const int t = threadIdx.x;
    const int b = blockIdx.x >> 6;          // 64 blocks per batch (1024 nodes/blk)

    if (t < Hh) sK[t] = knotsG[(size_t)b * Hh + t];
    for (int i = t; i < 6 * NSEG; i += TPB) sT[i] = segG[(size_t)b * 6 * NSEG + i];
    __syncthreads();

    const size_t n0 = ((size_t)blockIdx.x * TPB + t) * 4;
    bf16x4 xv = *(const bf16x4*)(xl + n0);
    float o[12];
#pragma unroll
    for (int i = 0; i < 4; ++i) {
        const float x = (float)xv[i];
        int pos = 0;
#pragma unroll
        for (int st = 32; st >= 1; st >>= 1)
            pos += (sK[pos + st - 1] < x) ? st : 0;
        pos += (sK[pos] < x) ? 1 : 0;       // pos = #knots < x, in [0,64]
        o[3 * i + 0] = fmaf(sT[3 * NSEG + pos], x, sT[0 * NSEG + pos]);
        o[3 * i + 1] = fmaf(sT[4 * NSEG + pos], x, sT[1 * NSEG + pos]);
        o[3 * i + 2] = fmaf(sT[5 * NSEG + pos], x, sT[2 * NSEG + pos]);
    }
    f32x4* po = (f32x4*)(out + n0 * 3);
    po[0] = f32x4{o[0], o[1], o[2],  o[3]};
    po[1] = f32x4{o[4], o[5], o[6],  o[7]};
    po[2] = f32x4{o[8], o[9], o[10], o[11]};
}

// ---------------------------------------------------------------------------
extern "C" void kernel_launch(void* const* d_in, const int* in_sizes, int n_in,
                              void* d_out, int out_size, void* d_ws, size_t ws_size,
                              hipStream_t stream) {
    const float* in  = (const float*)d_in[0];
    const float* mw1 = (const float*)d_in[1];
    const float* mb1 = (const float*)d_in[2];
    const float* mw2 = (const float*)d_in[3];
    const float* mb2 = (const float*)d_in[4];
    const float* iw1 = (const float*)d_in[5];
    const float* ib1 = (const float*)d_in[6];
    const float* iw2 = (const float*)d_in[7];
    const float* ib2 = (const float*)d_in[8];
    float* out = (float*)d_out;

    char* ws = (char*)d_ws;
    const size_t PART_SZ = (size_t)Bb * WPB_N * Hh * sizeof(float);  // 2 MiB
    float*  partials = (float*)(ws);
    float*  knotsG   = (float*)(ws + PART_SZ);             // 8 KiB
    float*  segG     = (float*)(ws + PART_SZ + 8192);      // ~49 KiB
    __bf16* xl       = (__bf16*)(ws + PART_SZ + 131072);   // 4 MiB

    const int nblocks = (Bb * Nn / NPW) / (TPB / 64);   // 2048
    hipLaunchKernelGGL(k_mphase, dim3(nblocks), dim3(TPB), 0, stream,
                       in, mw1, mb1, partials, xl);
    hipLaunchKernelGGL(k_combine, dim3(Bb), dim3(256), 0, stream,
                       partials, mw2, mb2, iw1, ib1, iw2, ib2, knotsG, segG);
    hipLaunchKernelGGL(k_iphase, dim3((Bb * Nn) / (TPB * 4)), dim3(TPB), 0, stream,
                       xl, knotsG, segG, out);
}

// Round 7
// 70.786 us; speedup vs baseline: 4.4259x; 4.4259x over previous
//
#include <hip/hip_runtime.h>
#include <hip/hip_bf16.h>

// Problem constants (match reference)
#define Bb   32
#define Nn   65536
#define Dd   16
#define Hh   64
#define Mm   32
#define OUTn 3

#define NPW   256              // nodes per wave in mphase
#define WPB_N (Nn / NPW)       // waves per batch = 256
#define TPB   256
#define NSEG  65               // 64 knots -> 65 segments

typedef __attribute__((ext_vector_type(8)))  __bf16 bf16x8;
typedef __attribute__((ext_vector_type(4)))  __bf16 bf16x4;
typedef __attribute__((ext_vector_type(16))) float  f32x16;
typedef __attribute__((ext_vector_type(4)))  float  f32x4;

static __device__ inline void split_bf(float w, __bf16& hi, __bf16& lo) {
    hi = (__bf16)w;                 // RNE hardware cvt
    lo = (__bf16)(w - (float)hi);   // residual
}

// ---------------------------------------------------------------------------
// Phase 1 via MFMA. vs R6 (which spilled: 553MB scratch writes):
//  * NO persistent bias vectors: C-init = 0, bias applied as fmax(acc+bias,0)
//    -> zero extra registers, nothing for the compiler to hoist
//  * keep 1-deep register prefetch + in-place relu/tree-sum
//  * __launch_bounds__(TPB) only -- no forced occupancy cap
__global__ __launch_bounds__(TPB) void k_mphase(
    const float* __restrict__ in, const float* __restrict__ mw1,
    const float* __restrict__ mb1, float* __restrict__ partials,
    __bf16* __restrict__ xlast)
{
    const int lane = threadIdx.x & 63;
    const int l31  = lane & 31;
    const int half = lane >> 5;                        // k-part: feats 8*half..
    const int wid  = blockIdx.x * (TPB / 64) + (threadIdx.x >> 6);
    const size_t node0 = (size_t)wid * NPW;

    // B fragments: B[k][col], k = 8*half + e. hi/lo split kills weight bias.
    bf16x8 bhiA, bloA, bhiB, bloB;
#pragma unroll
    for (int e = 0; e < 8; ++e) {
        const int k = 8 * half + e;
        __bf16 h, l;
        split_bf(mw1[k * Hh + l31], h, l);        bhiA[e] = h; bloA[e] = l;
        split_bf(mw1[k * Hh + 32 + l31], h, l);   bhiB[e] = h; bloB[e] = l;
    }
    const float biasA = mb1[l31];
    const float biasB = mb1[32 + l31];

    float hsumA = 0.f, hsumB = 0.f;
    const float* __restrict__ inw = in + node0 * Dd + (size_t)l31 * Dd + 8 * half;

    // prefetch tile 0
    f32x4 c0 = *(const f32x4*)(inw);
    f32x4 c1 = *(const f32x4*)(inw + 4);

#pragma unroll
    for (int s = 0; s < NPW / 32; ++s) {               // 8 tiles of 32 nodes
        f32x4 n0, n1;
        if (s < NPW / 32 - 1) {                        // compile-time pruned tail
            const float* apn = inw + (size_t)(s + 1) * 32 * Dd;
            n0 = *(const f32x4*)(apn);
            n1 = *(const f32x4*)(apn + 4);
        }

        bf16x8 a;
        a[0] = (__bf16)c0[0]; a[1] = (__bf16)c0[1];
        a[2] = (__bf16)c0[2]; a[3] = (__bf16)c0[3];
        a[4] = (__bf16)c1[0]; a[5] = (__bf16)c1[1];
        a[6] = (__bf16)c1[2]; a[7] = (__bf16)c1[3];

        f32x16 z{};   // zero C-init
        f32x16 accA = __builtin_amdgcn_mfma_f32_32x32x16_bf16(a, bloA, z, 0, 0, 0);
        accA        = __builtin_amdgcn_mfma_f32_32x32x16_bf16(a, bhiA, accA, 0, 0, 0);
        f32x16 accB = __builtin_amdgcn_mfma_f32_32x32x16_bf16(a, bloB, z, 0, 0, 0);
        accB        = __builtin_amdgcn_mfma_f32_32x32x16_bf16(a, bhiB, accB, 0, 0, 0);

        // bias + relu + tree-sum in place (no temps)
#pragma unroll
        for (int r = 0; r < 16; ++r) {
            accA[r] = fmaxf(accA[r] + biasA, 0.f);
            accB[r] = fmaxf(accB[r] + biasB, 0.f);
        }
#pragma unroll
        for (int st = 8; st >= 1; st >>= 1)
#pragma unroll
            for (int r = 0; r < st; ++r) {
                accA[r] += accA[r + st];
                accB[r] += accB[r + st];
            }
        hsumA += accA[0]; hsumB += accB[0];

        // x_last: lanes>=32 hold feat 15 of node (s*32 + l31) in c1.w
        float x15 = __shfl_xor(c1[3], 32, 64);
        if (lane < 32) xlast[node0 + (size_t)s * 32 + lane] = (__bf16)x15;

        c0 = n0; c1 = n1;
    }

    hsumA += __shfl_xor(hsumA, 32, 64);
    hsumB += __shfl_xor(hsumB, 32, 64);
    partials[(size_t)wid * Hh + lane] = (lane < 32) ? hsumA : hsumB;
}

// ---------------------------------------------------------------------------
// Reduce partials (parallel, coalesced) + build PWL tables.
// One block (256 thr) per batch. out_j(x) = A_j[seg] + B_j[seg]*x.
__global__ __launch_bounds__(256) void k_combine(
    const float* __restrict__ partials,
    const float* __restrict__ mw2, const float* __restrict__ mb2,
    const float* __restrict__ iw1, const float* __restrict__ ib1,
    const float* __restrict__ iw2, const float* __restrict__ ib2,
    float* __restrict__ knotsG, float* __restrict__ segG)
{
    __shared__ float red[4][Hh];
    __shared__ float sHs[Hh], sMs[Mm], sBase[Hh], sW[Hh], sKn[Hh], sSort[Hh];
    __shared__ float sIw2[Hh * OUTn];
    const int b = blockIdx.x;
    const int t = threadIdx.x;              // 0..255
    const int h = t & 63, slice = t >> 6;   // 4 slices x 64 h

    float s = 0.f;
    const float* p = partials + ((size_t)b * WPB_N + slice * 64) * Hh + h;
#pragma unroll 8
    for (int w = 0; w < 64; ++w) s += p[(size_t)w * Hh];
    red[slice][h] = s;
    for (int i = t; i < Hh * OUTn; i += 256) sIw2[i] = iw2[i];
    __syncthreads();

    if (t < Hh) sHs[t] = red[0][t] + red[1][t] + red[2][t] + red[3][t];
    __syncthreads();

    if (t < Mm) {
        float v = (float)Nn * mb2[t];
        for (int hh = 0; hh < Hh; ++hh) v = fmaf(sHs[hh], mw2[hh * Mm + t], v);
        sMs[t] = v;
    }
    __syncthreads();

    if (t < Hh) {
        float bs = ib1[t];
        for (int m = 0; m < Mm; ++m) bs = fmaf(sMs[m], iw1[m * Hh + t], bs);
        float w = iw1[Mm * Hh + t];
        sBase[t] = bs; sW[t] = w;
        float k = (w != 0.f) ? (-bs / w) : 1e15f;
        if (!(fabsf(k) < 1e15f)) k = 1e15f;   // NaN/inf guard
        sKn[t] = k;
    }
    __syncthreads();

    if (t < Hh) {                            // rank sort (64 values)
        float k = sKn[t];
        int r = 0;
        for (int j = 0; j < Hh; ++j) {
            float kj = sKn[j];
            r += (kj < k || (kj == k && j < t)) ? 1 : 0;
        }
        sSort[r] = k;
    }
    __syncthreads();

    if (t < Hh) knotsG[(size_t)b * Hh + t] = sSort[t];
    if (t < NSEG) {
        float lo = (t == 0)  ? sSort[0] - 1.0f      : sSort[t - 1];
        float hi = (t == Hh) ? sSort[Hh - 1] + 1.0f : sSort[t];
        float m  = 0.5f * lo + 0.5f * hi;
        float A0 = ib2[0], A1 = ib2[1], A2 = ib2[2], B0 = 0.f, B1 = 0.f, B2 = 0.f;
        for (int hh = 0; hh < Hh; ++hh) {
            float bs = sBase[hh], w = sW[hh];
            if (fmaf(w, m, bs) > 0.f) {
                A0 = fmaf(bs, sIw2[hh * 3 + 0], A0);
                A1 = fmaf(bs, sIw2[hh * 3 + 1], A1);
                A2 = fmaf(bs, sIw2[hh * 3 + 2], A2);
                B0 = fmaf(w,  sIw2[hh * 3 + 0], B0);
                B1 = fmaf(w,  sIw2[hh * 3 + 1], B1);
                B2 = fmaf(w,  sIw2[hh * 3 + 2], B2);
            }
        }
        float* sg = segG + (size_t)b * 6 * NSEG;   // SoA: [6][NSEG]
        sg[0 * NSEG + t] = A0; sg[1 * NSEG + t] = A1; sg[2 * NSEG + t] = A2;
        sg[3 * NSEG + t] = B0; sg[4 * NSEG + t] = B1; sg[5 * NSEG + t] = B2;
    }
}

// ---------------------------------------------------------------------------
// Phase 2: PWL eval. 4 nodes/thread; branchless binary search over 64 knots.
__global__ __launch_bounds__(TPB) void k_iphase(
    const __bf16* __restrict__ xl, const float* __restrict__ knotsG,
    const float* __restrict__ segG, float* __restrict__ out)
{
    __shared__ __align__(16) float sK[Hh];
    __shared__ float sT[6 * NSEG];
    const int t = threadIdx.x;
    const int b = blockIdx.x >> 6;          // 64 blocks per batch (1024 nodes/blk)

    if (t < Hh) sK[t] = knotsG[(size_t)b * Hh + t];
    for (int i = t; i < 6 * NSEG; i += TPB) sT[i] = segG[(size_t)b * 6 * NSEG + i];
    __syncthreads();

    const size_t n0 = ((size_t)blockIdx.x * TPB + t) * 4;
    bf16x4 xv = *(const bf16x4*)(xl + n0);
    float o[12];
#pragma unroll
    for (int i = 0; i < 4; ++i) {
        const float x = (float)xv[i];
        int pos = 0;
#pragma unroll
        for (int st = 32; st >= 1; st >>= 1)
            pos += (sK[pos + st - 1] < x) ? st : 0;
        pos += (sK[pos] < x) ? 1 : 0;       // pos = #knots < x, in [0,64]
        o[3 * i + 0] = fmaf(sT[3 * NSEG + pos], x, sT[0 * NSEG + pos]);
        o[3 * i + 1] = fmaf(sT[4 * NSEG + pos], x, sT[1 * NSEG + pos]);
        o[3 * i + 2] = fmaf(sT[5 * NSEG + pos], x, sT[2 * NSEG + pos]);
    }
    f32x4* po = (f32x4*)(out + n0 * 3);
    po[0] = f32x4{o[0], o[1], o[2],  o[3]};
    po[1] = f32x4{o[4], o[5], o[6],  o[7]};
    po[2] = f32x4{o[8], o[9], o[10], o[11]};
}

// ---------------------------------------------------------------------------
extern "C" void kernel_launch(void* const* d_in, const int* in_sizes, int n_in,
                              void* d_out, int out_size, void* d_ws, size_t ws_size,
                              hipStream_t stream) {
    const float* in  = (const float*)d_in[0];
    const float* mw1 = (const float*)d_in[1];
    const float* mb1 = (const float*)d_in[2];
    const float* mw2 = (const float*)d_in[3];
    const float* mb2 = (const float*)d_in[4];
    const float* iw1 = (const float*)d_in[5];
    const float* ib1 = (const float*)d_in[6];
    const float* iw2 = (const float*)d_in[7];
    const float* ib2 = (const float*)d_in[8];
    float* out = (float*)d_out;

    char* ws = (char*)d_ws;
    const size_t PART_SZ = (size_t)Bb * WPB_N * Hh * sizeof(float);  // 2 MiB
    float*  partials = (float*)(ws);
    float*  knotsG   = (float*)(ws + PART_SZ);             // 8 KiB
    float*  segG     = (float*)(ws + PART_SZ + 8192);      // ~49 KiB
    __bf16* xl       = (__bf16*)(ws + PART_SZ + 131072);   // 4 MiB

    const int nblocks = (Bb * Nn / NPW) / (TPB / 64);   // 2048
    hipLaunchKernelGGL(k_mphase, dim3(nblocks), dim3(TPB), 0, stream,
                       in, mw1, mb1, partials, xl);
    hipLaunchKernelGGL(k_combine, dim3(Bb), dim3(256), 0, stream,
                       partials, mw2, mb2, iw1, ib1, iw2, ib2, knotsG, segG);
    hipLaunchKernelGGL(k_iphase, dim3((Bb * Nn) / (TPB * 4)), dim3(TPB), 0, stream,
                       xl, knotsG, segG, out);
}

// Round 8
// 53.501 us; speedup vs baseline: 5.8558x; 1.3231x over previous
//
#include <hip/hip_runtime.h>
#include <hip/hip_bf16.h>

// Problem constants (match reference)
#define Bb   32
#define Nn   65536
#define Dd   16
#define Hh   64
#define Mm   32
#define OUTn 3

#define NPW   256              // nodes per wave in mphase
#define WPB_N (Nn / NPW)       // waves per batch = 256
#define TPB   256
#define NSEG  65               // 64 knots -> 65 segments

typedef __attribute__((ext_vector_type(8)))  __bf16 bf16x8;
typedef __attribute__((ext_vector_type(4)))  __bf16 bf16x4;
typedef __attribute__((ext_vector_type(16))) float  f32x16;
typedef __attribute__((ext_vector_type(4)))  float  f32x4;

static __device__ inline void split_bf(float w, __bf16& hi, __bf16& lo) {
    hi = (__bf16)w;                 // RNE hardware cvt
    lo = (__bf16)(w - (float)hi);   // residual
}

// ---------------------------------------------------------------------------
// Phase 1 via MFMA. vs R7 (252 VGPR, 2 waves/SIMD: compiler pipelined the
// fully-unrolled s-loop):
//  * #pragma unroll 1 on the s-loop -- deny cross-tile software pipelining
//  * manual 1-deep register prefetch inside the rolled loop
//  * live set ~= cur tile(8) + next tile(8) + acc(32) + bfrag(16) + misc
//    -> ~100 VGPR -> 4-5 waves/SIMD, ~2KiB in flight per wave
__global__ __launch_bounds__(TPB) void k_mphase(
    const float* __restrict__ in, const float* __restrict__ mw1,
    const float* __restrict__ mb1, float* __restrict__ partials,
    __bf16* __restrict__ xlast)
{
    const int lane = threadIdx.x & 63;
    const int l31  = lane & 31;
    const int half = lane >> 5;                        // k-part: feats 8*half..
    const int wid  = blockIdx.x * (TPB / 64) + (threadIdx.x >> 6);
    const size_t node0 = (size_t)wid * NPW;

    // B fragments: B[k][col], k = 8*half + e. hi/lo split kills weight bias.
    bf16x8 bhiA, bloA, bhiB, bloB;
#pragma unroll
    for (int e = 0; e < 8; ++e) {
        const int k = 8 * half + e;
        __bf16 h, l;
        split_bf(mw1[k * Hh + l31], h, l);        bhiA[e] = h; bloA[e] = l;
        split_bf(mw1[k * Hh + 32 + l31], h, l);   bhiB[e] = h; bloB[e] = l;
    }
    const float biasA = mb1[l31];
    const float biasB = mb1[32 + l31];

    float hsumA = 0.f, hsumB = 0.f;
    const float* __restrict__ inw = in + node0 * Dd + (size_t)l31 * Dd + 8 * half;

    // prefetch tile 0
    f32x4 c0 = *(const f32x4*)(inw);
    f32x4 c1 = *(const f32x4*)(inw + 4);

#pragma unroll 1
    for (int s = 0; s < NPW / 32; ++s) {               // 8 tiles of 32 nodes
        f32x4 n0, n1;
        if (s < NPW / 32 - 1) {                        // wave-uniform branch
            const float* apn = inw + (size_t)(s + 1) * 32 * Dd;
            n0 = *(const f32x4*)(apn);
            n1 = *(const f32x4*)(apn + 4);
        }

        bf16x8 a;
        a[0] = (__bf16)c0[0]; a[1] = (__bf16)c0[1];
        a[2] = (__bf16)c0[2]; a[3] = (__bf16)c0[3];
        a[4] = (__bf16)c1[0]; a[5] = (__bf16)c1[1];
        a[6] = (__bf16)c1[2]; a[7] = (__bf16)c1[3];

        f32x16 z{};   // zero C-init
        f32x16 accA = __builtin_amdgcn_mfma_f32_32x32x16_bf16(a, bloA, z, 0, 0, 0);
        accA        = __builtin_amdgcn_mfma_f32_32x32x16_bf16(a, bhiA, accA, 0, 0, 0);
        f32x16 accB = __builtin_amdgcn_mfma_f32_32x32x16_bf16(a, bloB, z, 0, 0, 0);
        accB        = __builtin_amdgcn_mfma_f32_32x32x16_bf16(a, bhiB, accB, 0, 0, 0);

        // bias + relu + tree-sum in place (no temps)
#pragma unroll
        for (int r = 0; r < 16; ++r) {
            accA[r] = fmaxf(accA[r] + biasA, 0.f);
            accB[r] = fmaxf(accB[r] + biasB, 0.f);
        }
#pragma unroll
        for (int st = 8; st >= 1; st >>= 1)
#pragma unroll
            for (int r = 0; r < st; ++r) {
                accA[r] += accA[r + st];
                accB[r] += accB[r + st];
            }
        hsumA += accA[0]; hsumB += accB[0];

        // x_last: lanes>=32 hold feat 15 of node (s*32 + l31) in c1.w
        float x15 = __shfl_xor(c1[3], 32, 64);
        if (lane < 32) xlast[node0 + (size_t)s * 32 + lane] = (__bf16)x15;

        c0 = n0; c1 = n1;
    }

    hsumA += __shfl_xor(hsumA, 32, 64);
    hsumB += __shfl_xor(hsumB, 32, 64);
    partials[(size_t)wid * Hh + lane] = (lane < 32) ? hsumA : hsumB;
}

// ---------------------------------------------------------------------------
// Reduce partials (parallel, coalesced) + build PWL tables.
// One block (256 thr) per batch. out_j(x) = A_j[seg] + B_j[seg]*x.
__global__ __launch_bounds__(256) void k_combine(
    const float* __restrict__ partials,
    const float* __restrict__ mw2, const float* __restrict__ mb2,
    const float* __restrict__ iw1, const float* __restrict__ ib1,
    const float* __restrict__ iw2, const float* __restrict__ ib2,
    float* __restrict__ knotsG, float* __restrict__ segG)
{
    __shared__ float red[4][Hh];
    __shared__ float sHs[Hh], sMs[Mm], sBase[Hh], sW[Hh], sKn[Hh], sSort[Hh];
    __shared__ float sIw2[Hh * OUTn];
    const int b = blockIdx.x;
    const int t = threadIdx.x;              // 0..255
    const int h = t & 63, slice = t >> 6;   // 4 slices x 64 h

    float s = 0.f;
    const float* p = partials + ((size_t)b * WPB_N + slice * 64) * Hh + h;
#pragma unroll 8
    for (int w = 0; w < 64; ++w) s += p[(size_t)w * Hh];
    red[slice][h] = s;
    for (int i = t; i < Hh * OUTn; i += 256) sIw2[i] = iw2[i];
    __syncthreads();

    if (t < Hh) sHs[t] = red[0][t] + red[1][t] + red[2][t] + red[3][t];
    __syncthreads();

    if (t < Mm) {
        float v = (float)Nn * mb2[t];
        for (int hh = 0; hh < Hh; ++hh) v = fmaf(sHs[hh], mw2[hh * Mm + t], v);
        sMs[t] = v;
    }
    __syncthreads();

    if (t < Hh) {
        float bs = ib1[t];
        for (int m = 0; m < Mm; ++m) bs = fmaf(sMs[m], iw1[m * Hh + t], bs);
        float w = iw1[Mm * Hh + t];
        sBase[t] = bs; sW[t] = w;
        float k = (w != 0.f) ? (-bs / w) : 1e15f;
        if (!(fabsf(k) < 1e15f)) k = 1e15f;   // NaN/inf guard
        sKn[t] = k;
    }
    __syncthreads();

    if (t < Hh) {                            // rank sort (64 values)
        float k = sKn[t];
        int r = 0;
        for (int j = 0; j < Hh; ++j) {
            float kj = sKn[j];
            r += (kj < k || (kj == k && j < t)) ? 1 : 0;
        }
        sSort[r] = k;
    }
    __syncthreads();

    if (t < Hh) knotsG[(size_t)b * Hh + t] = sSort[t];
    if (t < NSEG) {
        float lo = (t == 0)  ? sSort[0] - 1.0f      : sSort[t - 1];
        float hi = (t == Hh) ? sSort[Hh - 1] + 1.0f : sSort[t];
        float m  = 0.5f * lo + 0.5f * hi;
        float A0 = ib2[0], A1 = ib2[1], A2 = ib2[2], B0 = 0.f, B1 = 0.f, B2 = 0.f;
        for (int hh = 0; hh < Hh; ++hh) {
            float bs = sBase[hh], w = sW[hh];
            if (fmaf(w, m, bs) > 0.f) {
                A0 = fmaf(bs, sIw2[hh * 3 + 0], A0);
                A1 = fmaf(bs, sIw2[hh * 3 + 1], A1);
                A2 = fmaf(bs, sIw2[hh * 3 + 2], A2);
                B0 = fmaf(w,  sIw2[hh * 3 + 0], B0);
                B1 = fmaf(w,  sIw2[hh * 3 + 1], B1);
                B2 = fmaf(w,  sIw2[hh * 3 + 2], B2);
            }
        }
        float* sg = segG + (size_t)b * 6 * NSEG;   // SoA: [6][NSEG]
        sg[0 * NSEG + t] = A0; sg[1 * NSEG + t] = A1; sg[2 * NSEG + t] = A2;
        sg[3 * NSEG + t] = B0; sg[4 * NSEG + t] = B1; sg[5 * NSEG + t] = B2;
    }
}

// ---------------------------------------------------------------------------
// Phase 2: PWL eval. 4 nodes/thread; branchless binary search over 64 knots.
__global__ __launch_bounds__(TPB) void k_iphase(
    const __bf16* __restrict__ xl, const float* __restrict__ knotsG,
    const float* __restrict__ segG, float* __restrict__ out)
{
    __shared__ __align__(16) float sK[Hh];
    __shared__ float sT[6 * NSEG];
    const int t = threadIdx.x;
    const int b = blockIdx.x >> 6;          // 64 blocks per batch (1024 nodes/blk)

    if (t < Hh) sK[t] = knotsG[(size_t)b * Hh + t];
    for (int i = t; i < 6 * NSEG; i += TPB) sT[i] = segG[(size_t)b * 6 * NSEG + i];
    __syncthreads();

    const size_t n0 = ((size_t)blockIdx.x * TPB + t) * 4;
    bf16x4 xv = *(const bf16x4*)(xl + n0);
    float o[12];
#pragma unroll
    for (int i = 0; i < 4; ++i) {
        const float x = (float)xv[i];
        int pos = 0;
#pragma unroll
        for (int st = 32; st >= 1; st >>= 1)
            pos += (sK[pos + st - 1] < x) ? st : 0;
        pos += (sK[pos] < x) ? 1 : 0;       // pos = #knots < x, in [0,64]
        o[3 * i + 0] = fmaf(sT[3 * NSEG + pos], x, sT[0 * NSEG + pos]);
        o[3 * i + 1] = fmaf(sT[4 * NSEG + pos], x, sT[1 * NSEG + pos]);
        o[3 * i + 2] = fmaf(sT[5 * NSEG + pos], x, sT[2 * NSEG + pos]);
    }
    f32x4* po = (f32x4*)(out + n0 * 3);
    po[0] = f32x4{o[0], o[1], o[2],  o[3]};
    po[1] = f32x4{o[4], o[5], o[6],  o[7]};
    po[2] = f32x4{o[8], o[9], o[10], o[11]};
}

// ---------------------------------------------------------------------------
extern "C" void kernel_launch(void* const* d_in, const int* in_sizes, int n_in,
                              void* d_out, int out_size, void* d_ws, size_t ws_size,
                              hipStream_t stream) {
    const float* in  = (const float*)d_in[0];
    const float* mw1 = (const float*)d_in[1];
    const float* mb1 = (const float*)d_in[2];
    const float* mw2 = (const float*)d_in[3];
    const float* mb2 = (const float*)d_in[4];
    const float* iw1 = (const float*)d_in[5];
    const float* ib1 = (const float*)d_in[6];
    const float* iw2 = (const float*)d_in[7];
    const float* ib2 = (const float*)d_in[8];
    float* out = (float*)d_out;

    char* ws = (char*)d_ws;
    const size_t PART_SZ = (size_t)Bb * WPB_N * Hh * sizeof(float);  // 2 MiB
    float*  partials = (float*)(ws);
    float*  knotsG   = (float*)(ws + PART_SZ);             // 8 KiB
    float*  segG     = (float*)(ws + PART_SZ + 8192);      // ~49 KiB
    __bf16* xl       = (__bf16*)(ws + PART_SZ + 131072);   // 4 MiB

    const int nblocks = (Bb * Nn / NPW) / (TPB / 64);   // 2048
    hipLaunchKernelGGL(k_mphase, dim3(nblocks), dim3(TPB), 0, stream,
                       in, mw1, mb1, partials, xl);
    hipLaunchKernelGGL(k_combine, dim3(Bb), dim3(256), 0, stream,
                       partials, mw2, mb2, iw1, ib1, iw2, ib2, knotsG, segG);
    hipLaunchKernelGGL(k_iphase, dim3((Bb * Nn) / (TPB * 4)), dim3(TPB), 0, stream,
                       xl, knotsG, segG, out);
}

// Round 9
// 52.283 us; speedup vs baseline: 5.9923x; 1.0233x over previous
//
#include <hip/hip_runtime.h>
#include <hip/hip_bf16.h>

// Problem constants (match reference)
#define Bb   32
#define Nn   65536
#define Dd   16
#define Hh   64
#define Mm   32
#define OUTn 3

#define TPB    256
#define CHUNK  256                  // nodes per LDS chunk (16 KiB fp32)
#define NCH    8                    // chunks per block
#define SEGN   (CHUNK * NCH)        // 2048 nodes per block
#define NWAVES ((Bb * Nn) / 512)    // 4096 waves total (each wave: 512 nodes)
#define WPB    (NWAVES / Bb)        // 128 waves per batch
#define NSEG   65                   // 64 knots -> 65 segments

typedef __attribute__((ext_vector_type(8)))  __bf16 bf16x8;
typedef __attribute__((ext_vector_type(4)))  __bf16 bf16x4;
typedef __attribute__((ext_vector_type(16))) float  f32x16;
typedef __attribute__((ext_vector_type(4)))  float  f32x4;

static __device__ inline void split_bf(float w, __bf16& hi, __bf16& lo) {
    hi = (__bf16)w;                 // RNE hardware cvt
    lo = (__bf16)(w - (float)hi);   // residual
}

// async 16B global->LDS (direct-to-shared DMA; dest = wave-uniform base + lane*16)
typedef const __attribute__((address_space(1))) unsigned int gu32;
typedef __attribute__((address_space(3))) unsigned int lu32;
static __device__ __forceinline__ void gld16(const float* g, float* l) {
    __builtin_amdgcn_global_load_lds((gu32*)g, (lu32*)l, 16, 0, 0);
}

// ---------------------------------------------------------------------------
// Phase 1 via MFMA, LDS double-buffered streaming.
// LDS layout is c-major: granule(16B) index = quarter*CHUNK + node
//  -> staging: thread 'node' issues 4 gld16 (one per quarter), linear LDS dest
//  -> reading: fixed quarter => 32 consecutive granules per half-wave:
//     conflict-free ds_read_b128, no swizzle.
// Each wave stages exactly the 64 nodes it computes (self-contained).
__global__ __launch_bounds__(TPB) void k_mphase(
    const float* __restrict__ in, const float* __restrict__ mw1,
    const float* __restrict__ mb1, float* __restrict__ partials,
    __bf16* __restrict__ xlast)
{
    __shared__ float lds[2][CHUNK * Dd];            // 2 x 16 KiB

    const int tid  = threadIdx.x;
    const int lane = tid & 63;
    const int w    = tid >> 6;                      // wave in block (0..3)
    const int l31  = lane & 31;
    const int half = lane >> 5;
    const size_t blk0 = (size_t)blockIdx.x * SEGN;  // first node of this block

    // B fragments: B[k][col], k = 8*half + e. hi/lo split kills weight bias.
    bf16x8 bhiA, bloA, bhiB, bloB;
#pragma unroll
    for (int e = 0; e < 8; ++e) {
        const int k = 8 * half + e;
        __bf16 h, l;
        split_bf(mw1[k * Hh + l31], h, l);        bhiA[e] = h; bloA[e] = l;
        split_bf(mw1[k * Hh + 32 + l31], h, l);   bhiB[e] = h; bloB[e] = l;
    }
    const float biasA = mb1[l31];
    const float biasB = mb1[32 + l31];

    float hsumA = 0.f, hsumB = 0.f;

    // stage chunk c into buffer bf: node = tid, quarter q -> granule q*CHUNK+tid
    auto stage = [&](int bf, int c) {
        const float* src = in + (blk0 + (size_t)c * CHUNK + tid) * Dd;
#pragma unroll
        for (int q = 0; q < 4; ++q)
            gld16(src + q * 4, &lds[bf][(size_t)(q * CHUNK) * 4 + (size_t)w * 256]);
    };

    int cur = 0;
    stage(0, 0);
    __syncthreads();                                // vmcnt(0) drain: chunk 0 ready

#pragma unroll 1
    for (int c = 0; c < NCH; ++c) {
        if (c + 1 < NCH) stage(cur ^ 1, c + 1);     // prefetch next chunk

#pragma unroll
        for (int T = 0; T < 2; ++T) {               // 2 tiles of 32 nodes per wave
            const int nb = w * 64 + T * 32 + l31;   // node within chunk
            const int q0 = half * 2;
            f32x4 v0 = *(const f32x4*)&lds[cur][(size_t)(q0 * CHUNK + nb) * 4];
            f32x4 v1 = *(const f32x4*)&lds[cur][(size_t)((q0 + 1) * CHUNK + nb) * 4];

            bf16x8 a;
            a[0] = (__bf16)v0[0]; a[1] = (__bf16)v0[1];
            a[2] = (__bf16)v0[2]; a[3] = (__bf16)v0[3];
            a[4] = (__bf16)v1[0]; a[5] = (__bf16)v1[1];
            a[6] = (__bf16)v1[2]; a[7] = (__bf16)v1[3];

            f32x16 z{};   // zero C-init
            f32x16 accA = __builtin_amdgcn_mfma_f32_32x32x16_bf16(a, bloA, z, 0, 0, 0);
            accA        = __builtin_amdgcn_mfma_f32_32x32x16_bf16(a, bhiA, accA, 0, 0, 0);
            f32x16 accB = __builtin_amdgcn_mfma_f32_32x32x16_bf16(a, bloB, z, 0, 0, 0);
            accB        = __builtin_amdgcn_mfma_f32_32x32x16_bf16(a, bhiB, accB, 0, 0, 0);

            // bias + relu + tree-sum in place
#pragma unroll
            for (int r = 0; r < 16; ++r) {
                accA[r] = fmaxf(accA[r] + biasA, 0.f);
                accB[r] = fmaxf(accB[r] + biasB, 0.f);
            }
#pragma unroll
            for (int st = 8; st >= 1; st >>= 1)
#pragma unroll
                for (int r = 0; r < st; ++r) {
                    accA[r] += accA[r + st];
                    accB[r] += accB[r + st];
                }
            hsumA += accA[0]; hsumB += accB[0];

            // x_last: half=1 lanes read quarter 3 -> v1[3] = feat 15 of node nb
            float x15 = __shfl_xor(v1[3], 32, 64);
            if (lane < 32)
                xlast[blk0 + (size_t)c * CHUNK + w * 64 + T * 32 + lane] = (__bf16)x15;
        }

        __syncthreads();       // drains staged loads; releases cur for overwrite
        cur ^= 1;
    }

    hsumA += __shfl_xor(hsumA, 32, 64);
    hsumB += __shfl_xor(hsumB, 32, 64);
    const int wid = blockIdx.x * 4 + w;
    partials[(size_t)wid * Hh + lane] = (lane < 32) ? hsumA : hsumB;
}

// ---------------------------------------------------------------------------
// Reduce partials (parallel, coalesced) + build PWL tables.
// One block (256 thr) per batch. out_j(x) = A_j[seg] + B_j[seg]*x.
__global__ __launch_bounds__(256) void k_combine(
    const float* __restrict__ partials,
    const float* __restrict__ mw2, const float* __restrict__ mb2,
    const float* __restrict__ iw1, const float* __restrict__ ib1,
    const float* __restrict__ iw2, const float* __restrict__ ib2,
    float* __restrict__ knotsG, float* __restrict__ segG)
{
    __shared__ float red[4][Hh];
    __shared__ float sHs[Hh], sMs[Mm], sBase[Hh], sW[Hh], sKn[Hh], sSort[Hh];
    __shared__ float sIw2[Hh * OUTn];
    const int b = blockIdx.x;
    const int t = threadIdx.x;              // 0..255
    const int h = t & 63, slice = t >> 6;   // 4 slices x 32 rows

    float s = 0.f;
    const float* p = partials + ((size_t)b * WPB + slice * 32) * Hh + h;
#pragma unroll 8
    for (int ww = 0; ww < 32; ++ww) s += p[(size_t)ww * Hh];
    red[slice][h] = s;
    for (int i = t; i < Hh * OUTn; i += 256) sIw2[i] = iw2[i];
    __syncthreads();

    if (t < Hh) sHs[t] = red[0][t] + red[1][t] + red[2][t] + red[3][t];
    __syncthreads();

    if (t < Mm) {
        float v = (float)Nn * mb2[t];
        for (int hh = 0; hh < Hh; ++hh) v = fmaf(sHs[hh], mw2[hh * Mm + t], v);
        sMs[t] = v;
    }
    __syncthreads();

    if (t < Hh) {
        float bs = ib1[t];
        for (int m = 0; m < Mm; ++m) bs = fmaf(sMs[m], iw1[m * Hh + t], bs);
        float w = iw1[Mm * Hh + t];
        sBase[t] = bs; sW[t] = w;
        float k = (w != 0.f) ? (-bs / w) : 1e15f;
        if (!(fabsf(k) < 1e15f)) k = 1e15f;   // NaN/inf guard
        sKn[t] = k;
    }
    __syncthreads();

    if (t < Hh) {                            // rank sort (64 values)
        float k = sKn[t];
        int r = 0;
        for (int j = 0; j < Hh; ++j) {
            float kj = sKn[j];
            r += (kj < k || (kj == k && j < t)) ? 1 : 0;
        }
        sSort[r] = k;
    }
    __syncthreads();

    if (t < Hh) knotsG[(size_t)b * Hh + t] = sSort[t];
    if (t < NSEG) {
        float lo = (t == 0)  ? sSort[0] - 1.0f      : sSort[t - 1];
        float hi = (t == Hh) ? sSort[Hh - 1] + 1.0f : sSort[t];
        float m  = 0.5f * lo + 0.5f * hi;
        float A0 = ib2[0], A1 = ib2[1], A2 = ib2[2], B0 = 0.f, B1 = 0.f, B2 = 0.f;
        for (int hh = 0; hh < Hh; ++hh) {
            float bs = sBase[hh], w = sW[hh];
            if (fmaf(w, m, bs) > 0.f) {
                A0 = fmaf(bs, sIw2[hh * 3 + 0], A0);
                A1 = fmaf(bs, sIw2[hh * 3 + 1], A1);
                A2 = fmaf(bs, sIw2[hh * 3 + 2], A2);
                B0 = fmaf(w,  sIw2[hh * 3 + 0], B0);
                B1 = fmaf(w,  sIw2[hh * 3 + 1], B1);
                B2 = fmaf(w,  sIw2[hh * 3 + 2], B2);
            }
        }
        float* sg = segG + (size_t)b * 6 * NSEG;   // SoA: [6][NSEG]
        sg[0 * NSEG + t] = A0; sg[1 * NSEG + t] = A1; sg[2 * NSEG + t] = A2;
        sg[3 * NSEG + t] = B0; sg[4 * NSEG + t] = B1; sg[5 * NSEG + t] = B2;
    }
}

// ---------------------------------------------------------------------------
// Phase 2: PWL eval. 4 nodes/thread; branchless binary search over 64 knots.
__global__ __launch_bounds__(TPB) void k_iphase(
    const __bf16* __restrict__ xl, const float* __restrict__ knotsG,
    const float* __restrict__ segG, float* __restrict__ out)
{
    __shared__ __align__(16) float sK[Hh];
    __shared__ float sT[6 * NSEG];
    const int t = threadIdx.x;
    const int b = blockIdx.x >> 6;          // 64 blocks per batch (1024 nodes/blk)

    if (t < Hh) sK[t] = knotsG[(size_t)b * Hh + t];
    for (int i = t; i < 6 * NSEG; i += TPB) sT[i] = segG[(size_t)b * 6 * NSEG + i];
    __syncthreads();

    const size_t n0 = ((size_t)blockIdx.x * TPB + t) * 4;
    bf16x4 xv = *(const bf16x4*)(xl + n0);
    float o[12];
#pragma unroll
    for (int i = 0; i < 4; ++i) {
        const float x = (float)xv[i];
        int pos = 0;
#pragma unroll
        for (int st = 32; st >= 1; st >>= 1)
            pos += (sK[pos + st - 1] < x) ? st : 0;
        pos += (sK[pos] < x) ? 1 : 0;       // pos = #knots < x, in [0,64]
        o[3 * i + 0] = fmaf(sT[3 * NSEG + pos], x, sT[0 * NSEG + pos]);
        o[3 * i + 1] = fmaf(sT[4 * NSEG + pos], x, sT[1 * NSEG + pos]);
        o[3 * i + 2] = fmaf(sT[5 * NSEG + pos], x, sT[2 * NSEG + pos]);
    }
    f32x4* po = (f32x4*)(out + n0 * 3);
    po[0] = f32x4{o[0], o[1], o[2],  o[3]};
    po[1] = f32x4{o[4], o[5], o[6],  o[7]};
    po[2] = f32x4{o[8], o[9], o[10], o[11]};
}

// ---------------------------------------------------------------------------
extern "C" void kernel_launch(void* const* d_in, const int* in_sizes, int n_in,
                              void* d_out, int out_size, void* d_ws, size_t ws_size,
                              hipStream_t stream) {
    const float* in  = (const float*)d_in[0];
    const float* mw1 = (const float*)d_in[1];
    const float* mb1 = (const float*)d_in[2];
    const float* mw2 = (const float*)d_in[3];
    const float* mb2 = (const float*)d_in[4];
    const float* iw1 = (const float*)d_in[5];
    const float* ib1 = (const float*)d_in[6];
    const float* iw2 = (const float*)d_in[7];
    const float* ib2 = (const float*)d_in[8];
    float* out = (float*)d_out;

    char* ws = (char*)d_ws;
    const size_t PART_SZ = (size_t)NWAVES * Hh * sizeof(float);  // 1 MiB
    float*  partials = (float*)(ws);
    float*  knotsG   = (float*)(ws + PART_SZ);             // 8 KiB
    float*  segG     = (float*)(ws + PART_SZ + 8192);      // ~49 KiB
    __bf16* xl       = (__bf16*)(ws + PART_SZ + 131072);   // 4 MiB

    const int nblocks = (Bb * Nn) / SEGN;                  // 1024
    hipLaunchKernelGGL(k_mphase, dim3(nblocks), dim3(TPB), 0, stream,
                       in, mw1, mb1, partials, xl);
    hipLaunchKernelGGL(k_combine, dim3(Bb), dim3(256), 0, stream,
                       partials, mw2, mb2, iw1, ib1, iw2, ib2, knotsG, segG);
    hipLaunchKernelGGL(k_iphase, dim3((Bb * Nn) / (TPB * 4)), dim3(TPB), 0, stream,
                       xl, knotsG, segG, out);
}